// Round 1
// baseline (642.765 us; speedup 1.0000x reference)
//
#include <hip/hip_runtime.h>
#include <hip/hip_bf16.h>

// Problem constants (B=64, T=4096, D=256)
constexpr int DD  = 256;
constexpr int TT  = 4096;
constexpr int NBB = 64;
constexpr int TCC = 64;   // rows per chunk

typedef __bf16 bf16_t;
typedef __bf16 bf16x8 __attribute__((ext_vector_type(8)));
typedef float  f32x4  __attribute__((ext_vector_type(4)));

__device__ __forceinline__ float fast_tanh(float x) {
  // tanh(x) = 1 - 2/(exp(2x)+1); exact at +-inf, ~1e-6 rel error
  float e = __expf(x + x);
  return 1.0f - __fdividef(2.0f, e + 1.0f);
}

// ---- prep: WkT_bf16[n][d] = bf16(Wk[d][n]) --------------------------------
__global__ __launch_bounds__(256) void prep_wkT_kernel(
    const float* __restrict__ Wk, unsigned short* __restrict__ wkT) {
  int d = blockIdx.x;       // 256 blocks
  int n = threadIdx.x;      // 256 threads, coalesced read of row d
  union { bf16_t h; unsigned short u; } cv;
  cv.h = (bf16_t)Wk[d * DD + n];
  wkT[n * DD + d] = cv.u;
}

// ---- prep: qb2[b][d] = x[b,T-1,:]@Wq + bq + bk ----------------------------
__global__ __launch_bounds__(256) void prep_q_kernel(
    const float* __restrict__ x, const float* __restrict__ Wq,
    const float* __restrict__ bq, const float* __restrict__ bk,
    float* __restrict__ qb2) {
  __shared__ float xl[DD];
  int b = blockIdx.x, tid = threadIdx.x;
  xl[tid] = x[((size_t)b * TT + (TT - 1)) * DD + tid];
  __syncthreads();
  float a = bq[tid] + bk[tid];
  for (int k = 0; k < DD; ++k) a = fmaf(xl[k], Wq[k * DD + tid], a);
  qb2[b * DD + tid] = a;
}

// ---- main: fused k-GEMM + tanh-score + online softmax + c = sum w*x -------
__global__ __launch_bounds__(256) void fused_scores_kernel(
    const float* __restrict__ x, const unsigned short* __restrict__ wkT,
    const float* __restrict__ qb2, const float* __restrict__ wout,
    float* __restrict__ partials, int nchunk, int split) {
  __shared__ __align__(16) unsigned short xs[TCC * DD];  // 32 KB bf16, swizzled
  __shared__ float qw[2 * DD];     // qb2 | wout
  __shared__ float epart[4 * TCC]; // per-wave score partials
  __shared__ float escr[TCC];
  __shared__ float wbuf[TCC];

  const int tid = threadIdx.x;
  const int b   = blockIdx.y;
  const int bx  = blockIdx.x;
  const int wid = tid >> 6;
  const int l   = tid & 63;
  const int l15 = l & 15;
  const int lg  = l >> 4;

  qw[tid]      = qb2[b * DD + tid];
  qw[DD + tid] = wout[tid];
  __syncthreads();

  // per-lane score-phase constants (cols owned by this lane)
  float qcol[4], wcol[4];
#pragma unroll
  for (int nt = 0; nt < 4; ++nt) {
    int col = wid * 64 + nt * 16 + l15;
    qcol[nt] = qw[col];
    wcol[nt] = qw[DD + col];
  }

  float m_run = -INFINITY, s_run = 0.0f, cacc = 0.0f;

  for (int j = 0; j < nchunk; ++j) {
    const int t0 = (bx * nchunk + j) * TCC;
    const float* xc = x + ((size_t)b * TT + t0) * DD;

    // ---- stage x chunk -> LDS bf16 (XOR swizzle: byte ^= (row&7)<<4) ----
#pragma unroll
    for (int i = 0; i < 16; ++i) {
      int f = i * 256 + tid;          // float4 index in chunk
      float4 v = reinterpret_cast<const float4*>(xc)[f];
      int row = f >> 6;               // 64 float4 per row
      int c4  = f & 63;
      union { bf16_t h[4]; uint2 u; } pk;
      pk.h[0] = (bf16_t)v.x; pk.h[1] = (bf16_t)v.y;
      pk.h[2] = (bf16_t)v.z; pk.h[3] = (bf16_t)v.w;
      int byte = (row * 512 + c4 * 8) ^ ((row & 7) << 4);
      *reinterpret_cast<uint2*>(reinterpret_cast<char*>(xs) + byte) = pk.u;
    }
    __syncthreads();

    // ---- k-GEMM: [64x256]x[256x256], wave wid owns cols [64*wid, +64) ----
    f32x4 acc[4][4];
#pragma unroll
    for (int mt = 0; mt < 4; ++mt)
#pragma unroll
      for (int nt = 0; nt < 4; ++nt)
        acc[mt][nt] = f32x4{0.f, 0.f, 0.f, 0.f};

#pragma unroll
    for (int ks = 0; ks < 8; ++ks) {
      bf16x8 bfr[4];
#pragma unroll
      for (int nt = 0; nt < 4; ++nt) {
        int n = wid * 64 + nt * 16 + l15;
        bfr[nt] = *reinterpret_cast<const bf16x8*>(wkT + n * DD + ks * 32 + lg * 8);
      }
      bf16x8 afr[4];
#pragma unroll
      for (int mt = 0; mt < 4; ++mt) {
        int row  = mt * 16 + l15;
        int byte = (row * 512 + ks * 64 + lg * 16) ^ ((row & 7) << 4);
        afr[mt] = *reinterpret_cast<const bf16x8*>(reinterpret_cast<char*>(xs) + byte);
      }
#pragma unroll
      for (int mt = 0; mt < 4; ++mt)
#pragma unroll
        for (int nt = 0; nt < 4; ++nt)
          acc[mt][nt] = __builtin_amdgcn_mfma_f32_16x16x32_bf16(
              afr[mt], bfr[nt], acc[mt][nt], 0, 0, 0);
    }

    // ---- scores: e_t += sum_col tanh(qb2+k) * wout (this wave's 64 cols) ----
    float rs[4][4];
#pragma unroll
    for (int mt = 0; mt < 4; ++mt)
#pragma unroll
      for (int r = 0; r < 4; ++r) rs[mt][r] = 0.0f;

#pragma unroll
    for (int nt = 0; nt < 4; ++nt) {
#pragma unroll
      for (int mt = 0; mt < 4; ++mt)
#pragma unroll
        for (int r = 0; r < 4; ++r)
          rs[mt][r] += fast_tanh(qcol[nt] + acc[mt][nt][r]) * wcol[nt];
    }
    // reduce across 16 lanes (cols) within each lane-group
#pragma unroll
    for (int s = 1; s < 16; s <<= 1) {
#pragma unroll
      for (int mt = 0; mt < 4; ++mt)
#pragma unroll
        for (int r = 0; r < 4; ++r)
          rs[mt][r] += __shfl_xor(rs[mt][r], s, 64);
    }
    if (l15 == 0) {
#pragma unroll
      for (int mt = 0; mt < 4; ++mt)
#pragma unroll
        for (int r = 0; r < 4; ++r)
          epart[wid * TCC + mt * 16 + lg * 4 + r] = rs[mt][r];
    }
    __syncthreads();

    if (tid < TCC)
      escr[tid] = epart[tid] + epart[TCC + tid] + epart[2 * TCC + tid] + epart[3 * TCC + tid];
    __syncthreads();

    // block-uniform max + weights
    float m_c = -INFINITY;
#pragma unroll 8
    for (int t = 0; t < TCC; ++t) m_c = fmaxf(m_c, escr[t]);
    float m_new = fmaxf(m_run, m_c);
    if (tid < TCC) wbuf[tid] = __expf(escr[tid] - m_new);
    __syncthreads();

    // online rescale + weighted accumulation of fp32 x (L2-hot re-read)
    float scale = __expf(m_run - m_new);
    cacc *= scale;
    float s_new = s_run * scale;
    const float* xg = x + ((size_t)b * TT + t0) * DD + tid;
    for (int t = 0; t < TCC; ++t) {
      float wt = wbuf[t];
      s_new += wt;
      cacc = fmaf(wt, xg[t * DD], cacc);
    }
    m_run = m_new;
    s_run = s_new;
    __syncthreads();
  }

  float* p = partials + (size_t)(b * split + bx) * 258;
  if (tid == 0) { p[0] = m_run; p[1] = s_run; }
  p[2 + tid] = cacc;
}

// ---- combine partials, out = (c/s)@Wv + bv --------------------------------
__global__ __launch_bounds__(256) void combine_kernel(
    const float* __restrict__ partials, const float* __restrict__ Wv,
    const float* __restrict__ bv, float* __restrict__ out, int split) {
  __shared__ float att[DD];
  int b = blockIdx.x, tid = threadIdx.x;
  const float* pb = partials + (size_t)b * split * 258;
  float M = -INFINITY;
  for (int j = 0; j < split; ++j) M = fmaxf(M, pb[j * 258]);
  float S = 0.0f, C = 0.0f;
  for (int j = 0; j < split; ++j) {
    const float* p = pb + j * 258;
    float sc = __expf(p[0] - M);
    S += p[1] * sc;
    C = fmaf(p[2 + tid], sc, C);
  }
  att[tid] = C;
  __syncthreads();
  float inv = __fdividef(1.0f, S);
  float sum = 0.0f;
  for (int k = 0; k < DD; ++k) sum = fmaf(att[k], Wv[k * DD + tid], sum);
  out[b * DD + tid] = fmaf(sum, inv, bv[tid]);
}

extern "C" void kernel_launch(void* const* d_in, const int* in_sizes, int n_in,
                              void* d_out, int out_size, void* d_ws, size_t ws_size,
                              hipStream_t stream) {
  const float* x    = (const float*)d_in[0];
  const float* Wq   = (const float*)d_in[1];
  const float* bq   = (const float*)d_in[2];
  const float* Wk   = (const float*)d_in[3];
  const float* bk   = (const float*)d_in[4];
  const float* Wv   = (const float*)d_in[5];
  const float* bv   = (const float*)d_in[6];
  const float* Wout = (const float*)d_in[7];
  float* out = (float*)d_out;

  char* ws = (char*)d_ws;
  unsigned short* wkT = (unsigned short*)ws;            // 128 KB
  float* qb2 = (float*)(ws + 131072);                   // 64 KB
  float* partials = (float*)(ws + 131072 + 65536);

  int split = 64;   // blocks per batch over T; shrink if workspace is small
  while (split > 1 &&
         (size_t)196608 + (size_t)NBB * split * 258 * 4 > ws_size)
    split >>= 1;
  int nchunk = 64 / split;

  prep_wkT_kernel<<<dim3(256), dim3(256), 0, stream>>>(Wk, wkT);
  prep_q_kernel<<<dim3(64), dim3(256), 0, stream>>>(x, Wq, bq, bk, qb2);
  fused_scores_kernel<<<dim3(split, NBB), dim3(256), 0, stream>>>(
      x, wkT, qb2, Wout, partials, nchunk, split);
  combine_kernel<<<dim3(64), dim3(256), 0, stream>>>(partials, Wv, bv, out, split);
}

// Round 3
// 413.126 us; speedup vs baseline: 1.5559x; 1.5559x over previous
//
#include <hip/hip_runtime.h>
#include <hip/hip_bf16.h>

// Problem constants (B=64, T=4096, D=256)
constexpr int DD  = 256;
constexpr int TT  = 4096;
constexpr int NBB = 64;
constexpr int TCC = 32;                    // rows per chunk
constexpr int SPLIT = 8;                   // blocks per batch over T
constexpr int NCHUNK = (TT / SPLIT) / TCC; // 16 chunks per block
constexpr int CHUNK_BYTES = TCC * DD * 4;  // 32 KB fp32

typedef __bf16 bf16_t;
typedef __bf16 bf16x8 __attribute__((ext_vector_type(8)));
typedef float  f32x4  __attribute__((ext_vector_type(4)));

__device__ __forceinline__ float fast_tanh(float x) {
  // tanh(x) = 1 - 2/(exp(2x)+1); ~1e-6 rel error
  float e = __expf(x + x);
  return 1.0f - __fdividef(2.0f, e + 1.0f);
}

__device__ __forceinline__ void gload_lds16(const void* g, void* l) {
  __builtin_amdgcn_global_load_lds(
      (const __attribute__((address_space(1))) unsigned int*)g,
      (__attribute__((address_space(3))) unsigned int*)l, 16, 0, 0);
}

// ---- prep: WkT_bf16[n][d] = bf16(Wk[d][n]) --------------------------------
__global__ __launch_bounds__(256) void prep_wkT_kernel(
    const float* __restrict__ Wk, unsigned short* __restrict__ wkT) {
  int d = blockIdx.x;
  int n = threadIdx.x;
  union { bf16_t h; unsigned short u; } cv;
  cv.h = (bf16_t)Wk[d * DD + n];
  wkT[n * DD + d] = cv.u;
}

// ---- prep: qb2[b][d] = x[b,T-1,:]@Wq + bq + bk ----------------------------
__global__ __launch_bounds__(256) void prep_q_kernel(
    const float* __restrict__ x, const float* __restrict__ Wq,
    const float* __restrict__ bq, const float* __restrict__ bk,
    float* __restrict__ qb2) {
  __shared__ float xl[DD];
  int b = blockIdx.x, tid = threadIdx.x;
  xl[tid] = x[((size_t)b * TT + (TT - 1)) * DD + tid];
  __syncthreads();
  float a = bq[tid] + bk[tid];
  for (int k = 0; k < DD; ++k) a = fmaf(xl[k], Wq[k * DD + tid], a);
  qb2[b * DD + tid] = a;
}

// ---- main: async-pipelined k-GEMM + tanh-score + softmax-accum ------------
// grid (SPLIT, NBB), 256 threads. Per chunk (32 rows):
//   STAGE(next chunk, global_load_lds fp32, pre-swizzled src) overlaps
//   MFMA (bf16 cvt on the fly) + tanh/score + exp-weight + fp32 x-accum.
// No softmax max-tracking: |e| <= sum|Wout| ~ 8 -> exp safe in fp32.
__global__ __launch_bounds__(256, 2) void fused_scores_kernel(
    const float* __restrict__ x, const unsigned short* __restrict__ wkT,
    const float* __restrict__ qb2, const float* __restrict__ wout,
    float* __restrict__ partials) {
  __shared__ __align__(16) char xs[2 * CHUNK_BYTES];  // 64 KB double buffer
  __shared__ float epart[4 * TCC];
  __shared__ float wbuf[TCC];

  const int tid = threadIdx.x;
  const int b   = blockIdx.y;
  const int bx  = blockIdx.x;
  const int wid = tid >> 6;
  const int l   = tid & 63;
  const int l15 = l & 15;
  const int lg  = l >> 4;

  // B fragments (wkT) held in registers for the whole kernel: 4 nt x 8 ks
  bf16x8 bfr[4][8];
#pragma unroll
  for (int nt = 0; nt < 4; ++nt) {
    const unsigned short* wp = wkT + (size_t)(wid * 64 + nt * 16 + l15) * DD + lg * 8;
#pragma unroll
    for (int ks = 0; ks < 8; ++ks)
      bfr[nt][ks] = *reinterpret_cast<const bf16x8*>(wp + ks * 32);
  }

  float qcol[4], wcol[4];
#pragma unroll
  for (int nt = 0; nt < 4; ++nt) {
    int col = wid * 64 + nt * 16 + l15;
    qcol[nt] = qb2[b * DD + col];
    wcol[nt] = wout[col];
  }

  const char* xbase =
      (const char*)(x + ((size_t)b * TT + (size_t)bx * (TT / SPLIT)) * DD);

  // STAGE: linear LDS dest (wave-uniform base), inverse-swizzled global src.
  // LDS[row][off] holds global byte (off ^ ((row&7)<<4)) of row.
  auto stage = [&](int bufidx, int chunk) {
    const char* xc = xbase + (size_t)chunk * CHUNK_BYTES;
    char* lds = xs + bufidx * CHUNK_BYTES + wid * 8192;
#pragma unroll
    for (int i = 0; i < 8; ++i) {
      int row = wid * 8 + i;           // row & 7 == i
      gload_lds16(xc + row * 1024 + ((l * 16) ^ (i << 4)), lds + i * 1024);
    }
  };

  float s_run = 0.0f, cacc = 0.0f;

  stage(0, 0);
  asm volatile("s_waitcnt vmcnt(0)" ::: "memory");
  __syncthreads();

  for (int j = 0; j < NCHUNK; ++j) {
    const char* xb = xs + (j & 1) * CHUNK_BYTES;
    if (j + 1 < NCHUNK) stage((j + 1) & 1, j + 1);

    // ---- k-GEMM: [32 x 256] x [256 x 256]; wave owns 64 cols -------------
    f32x4 acc[2][4];
#pragma unroll
    for (int mt = 0; mt < 2; ++mt)
#pragma unroll
      for (int nt = 0; nt < 4; ++nt)
        acc[mt][nt] = f32x4{0.f, 0.f, 0.f, 0.f};

    const int sw = (l15 & 7) << 4;
#pragma unroll
    for (int ks = 0; ks < 8; ++ks) {
      bf16x8 afr[2];
#pragma unroll
      for (int mt = 0; mt < 2; ++mt) {
        int row = mt * 16 + l15;
        const f32x4 a0 = *(const f32x4*)(xb + row * 1024 + ((ks * 128 + lg * 32) ^ sw));
        const f32x4 a1 = *(const f32x4*)(xb + row * 1024 + ((ks * 128 + lg * 32 + 16) ^ sw));
        bf16x8 t;
        t[0] = (bf16_t)a0[0]; t[1] = (bf16_t)a0[1];
        t[2] = (bf16_t)a0[2]; t[3] = (bf16_t)a0[3];
        t[4] = (bf16_t)a1[0]; t[5] = (bf16_t)a1[1];
        t[6] = (bf16_t)a1[2]; t[7] = (bf16_t)a1[3];
        afr[mt] = t;
      }
#pragma unroll
      for (int mt = 0; mt < 2; ++mt)
#pragma unroll
        for (int nt = 0; nt < 4; ++nt)
          acc[mt][nt] = __builtin_amdgcn_mfma_f32_16x16x32_bf16(
              afr[mt], bfr[nt][ks], acc[mt][nt], 0, 0, 0);
    }

    // ---- scores: e_t += sum_col tanh(qb2+k)*wout over this wave's cols ----
    float rs[2][4];
#pragma unroll
    for (int mt = 0; mt < 2; ++mt)
#pragma unroll
      for (int r = 0; r < 4; ++r) rs[mt][r] = 0.0f;
#pragma unroll
    for (int nt = 0; nt < 4; ++nt) {
      float q = qcol[nt], w = wcol[nt];
#pragma unroll
      for (int mt = 0; mt < 2; ++mt)
#pragma unroll
        for (int r = 0; r < 4; ++r)
          rs[mt][r] += fast_tanh(q + acc[mt][nt][r]) * w;
    }
#pragma unroll
    for (int s = 1; s < 16; s <<= 1) {
#pragma unroll
      for (int mt = 0; mt < 2; ++mt)
#pragma unroll
        for (int r = 0; r < 4; ++r)
          rs[mt][r] += __shfl_xor(rs[mt][r], s, 64);
    }
    if (l15 == 0) {
#pragma unroll
      for (int mt = 0; mt < 2; ++mt)
#pragma unroll
        for (int r = 0; r < 4; ++r)
          epart[wid * TCC + mt * 16 + lg * 4 + r] = rs[mt][r];
    }
    __syncthreads();

    if (tid < TCC)
      wbuf[tid] = __expf(epart[tid] + epart[TCC + tid] +
                         epart[2 * TCC + tid] + epart[3 * TCC + tid]);
    __syncthreads();

    // ---- weighted accumulation of fp32 x from LDS ------------------------
#pragma unroll 8
    for (int t = 0; t < TCC; ++t) {
      float wt = wbuf[t];
      s_run += wt;
      float xv = *(const float*)(xb + t * 1024 + ((tid * 4) ^ ((t & 7) << 4)));
      cacc = fmaf(wt, xv, cacc);
    }

    asm volatile("s_waitcnt vmcnt(0)" ::: "memory");
    __syncthreads();
  }

  float* p = partials + ((size_t)b * SPLIT + bx) * 257;
  if (tid == 0) p[0] = s_run;
  p[1 + tid] = cacc;
}

// ---- combine partials, out = (C/S)@Wv + bv --------------------------------
__global__ __launch_bounds__(256) void combine_kernel(
    const float* __restrict__ partials, const float* __restrict__ Wv,
    const float* __restrict__ bv, float* __restrict__ out) {
  __shared__ float att[DD];
  int b = blockIdx.x, tid = threadIdx.x;
  const float* pb = partials + (size_t)b * SPLIT * 257;
  float S = 0.0f, C = 0.0f;
  for (int j = 0; j < SPLIT; ++j) {
    S += pb[j * 257];
    C += pb[j * 257 + 1 + tid];
  }
  att[tid] = C;
  __syncthreads();
  float inv = __fdividef(1.0f, S);
  float sum = 0.0f;
  for (int k = 0; k < DD; ++k) sum = fmaf(att[k], Wv[k * DD + tid], sum);
  out[b * DD + tid] = fmaf(sum, inv, bv[tid]);
}

extern "C" void kernel_launch(void* const* d_in, const int* in_sizes, int n_in,
                              void* d_out, int out_size, void* d_ws, size_t ws_size,
                              hipStream_t stream) {
  const float* x    = (const float*)d_in[0];
  const float* Wq   = (const float*)d_in[1];
  const float* bq   = (const float*)d_in[2];
  const float* Wk   = (const float*)d_in[3];
  const float* bk   = (const float*)d_in[4];
  const float* Wv   = (const float*)d_in[5];
  const float* bv   = (const float*)d_in[6];
  const float* Wout = (const float*)d_in[7];
  float* out = (float*)d_out;

  char* ws = (char*)d_ws;
  unsigned short* wkT = (unsigned short*)ws;       // 128 KB
  float* qb2      = (float*)(ws + 131072);         // 64 KB
  float* partials = (float*)(ws + 131072 + 65536); // 64*8*257*4 = 514 KB

  prep_wkT_kernel<<<dim3(256), dim3(256), 0, stream>>>(Wk, wkT);
  prep_q_kernel<<<dim3(64), dim3(256), 0, stream>>>(x, Wq, bq, bk, qb2);
  fused_scores_kernel<<<dim3(SPLIT, NBB), dim3(256), 0, stream>>>(
      x, wkT, qb2, Wout, partials);
  combine_kernel<<<dim3(64), dim3(256), 0, stream>>>(partials, Wv, bv, out);
}